// Round 5
// baseline (1009.708 us; speedup 1.0000x reference)
//
#include <hip/hip_runtime.h>
#include <hip/hip_cooperative_groups.h>
#include <math.h>

namespace cg = cooperative_groups;

#define N_NODES 50000
#define N_EDGES 500000
#define DIM 64
#define NUM_RELS 16
#define NBLK 1024
#define NTHR 256

// ---------------- ws layout (4-byte words) ----------------
// [192,208)   counts[16]
// [228,244)   cursor[16]
// [256,+N)    sn[N]
// [50256,+N)  dn[N]
// [100352,..) rec[E] as int4 {src,dst,ae_bits,0}  (byte off 401408, 16B aligned)

// ---- phase 0: zero the cross-block accumulators (must be fenced before
//      any phase1 histogram flush — this was the R4 race) ----
__device__ void phase0(int* counts, int* cursor) {
    if (blockIdx.x == 0 && threadIdx.x < NUM_RELS) {
        counts[threadIdx.x] = 0;
        cursor[threadIdx.x] = 0;
    }
}

// ---- phase 1: node score scalars, zero out, rel histogram ----
__device__ void phase1(const float* __restrict__ h,
                       const float* __restrict__ W_shared,
                       const float* __restrict__ W_attn,
                       const int* __restrict__ rel,
                       float* __restrict__ sn, float* __restrict__ dn,
                       float4* __restrict__ out4,
                       int* counts) {
    __shared__ float sus[64], sud[64];
    __shared__ int histp1[NUM_RELS];
    const int t = threadIdx.x, bid = blockIdx.x;
    if (t < 64) {
        float us = 0.f, ud = 0.f;
        for (int o = 0; o < 64; ++o) {
            float w = W_shared[o * 64 + t];
            us = fmaf(w, W_attn[o],       us);
            ud = fmaf(w, W_attn[128 + o], ud);
        }
        sus[t] = us; sud[t] = ud;
    }
    if (t < NUM_RELS) histp1[t] = 0;
    __syncthreads();

    for (int n = bid * NTHR + t; n < N_NODES; n += NBLK * NTHR) {
        const float* hp = h + (size_t)n * DIM;
        float s = 0.f, d = 0.f;
#pragma unroll
        for (int i = 0; i < 64; i += 4) {
            float4 v = *(const float4*)(hp + i);
            s = fmaf(v.x, sus[i], s);     s = fmaf(v.y, sus[i + 1], s);
            s = fmaf(v.z, sus[i + 2], s); s = fmaf(v.w, sus[i + 3], s);
            d = fmaf(v.x, sud[i], d);     d = fmaf(v.y, sud[i + 1], d);
            d = fmaf(v.z, sud[i + 2], d); d = fmaf(v.w, sud[i + 3], d);
        }
        sn[n] = s; dn[n] = d;
        float4 z = make_float4(0.f, 0.f, 0.f, 0.f);
#pragma unroll
        for (int i = 0; i < 16; ++i) out4[(size_t)n * 16 + i] = z;
    }
    for (int e = bid * NTHR + t; e < N_EDGES; e += NBLK * NTHR)
        atomicAdd(&histp1[rel[e]], 1);
    __syncthreads();
    if (t < NUM_RELS && histp1[t]) atomicAdd(&counts[t], histp1[t]);
}

// ---- phase 2: per-edge ae + scatter packed records into rel-sorted order ----
__device__ void phase2(const float4* __restrict__ he4,
                       const int* __restrict__ src, const int* __restrict__ dst,
                       const int* __restrict__ rel,
                       const float* __restrict__ W_shared,
                       const float* __restrict__ W_attn,
                       const float* __restrict__ sn, const float* __restrict__ dn,
                       const int* counts, int* cursor, int4* __restrict__ rec) {
    __shared__ float sve[64];
    __shared__ int hist[NUM_RELS], bbase[NUM_RELS], soffs[NUM_RELS];
    const int t = threadIdx.x, bid = blockIdx.x;
    if (t < 64) {
        float ve = 0.f;
        for (int o = 0; o < 64; ++o)
            ve = fmaf(W_shared[o * 64 + t], W_attn[64 + o], ve);
        sve[t] = ve;
    }
    if (t == 0) {
        int acc = 0;
        for (int j = 0; j < NUM_RELS; ++j) { soffs[j] = acc; acc += counts[j]; }
    }
    for (int e0 = bid * NTHR; e0 < N_EDGES; e0 += NBLK * NTHR) {
        __syncthreads();
        if (t < NUM_RELS) hist[t] = 0;
        __syncthreads();
        int e = e0 + t;
        bool valid = (e < N_EDGES);
        int r = 0, lpos = 0, s_ = 0, d_ = 0; float aev = 0.f;
        if (valid) {
            s_ = src[e]; d_ = dst[e]; r = rel[e];
            const float4* hr = he4 + (size_t)e * 16;
            float acc = 0.f;
#pragma unroll
            for (int i = 0; i < 16; ++i) {
                float4 v = hr[i];
                float4 u = *(const float4*)(sve + 4 * i);
                acc += v.x * u.x + v.y * u.y + v.z * u.z + v.w * u.w;
            }
            aev = acc + sn[s_] + dn[d_];
            lpos = atomicAdd(&hist[r], 1);
        }
        __syncthreads();
        if (t < NUM_RELS) bbase[t] = hist[t] ? atomicAdd(&cursor[t], hist[t]) : 0;
        __syncthreads();
        if (valid) rec[soffs[r] + bbase[r] + lpos] =
                       make_int4(s_, d_, __float_as_int(aev), 0);
    }
}

// ---- phase 3: main edge compute. wave = relation; W column pinned in regs;
//      records + h row via uniform s_load; native fp32 atomics out. ----
__device__ void phase3(const float* __restrict__ h,
                       const float* __restrict__ W_rel,
                       const int* counts, const int4* __restrict__ rec,
                       float* __restrict__ out) {
    const int t = threadIdx.x, bid = blockIdx.x;
    const int lane = t & 63;
    const int wib  = __builtin_amdgcn_readfirstlane(t >> 6);
    const int r    = bid & 15;
    const int g    = bid >> 4;            // 0..63
    const int wr   = g * 4 + wib;         // 0..255
    const int WPR  = 256;

    int begin = 0, cr = 0;
#pragma unroll
    for (int j = 0; j < NUM_RELS; ++j) {
        int c = counts[j];
        if (j < r) begin += c;
        if (j == r) cr = c;
    }
    begin = __builtin_amdgcn_readfirstlane(begin);
    const int end = __builtin_amdgcn_readfirstlane(begin + cr);

    float w[64];
    const float* wb = W_rel + (size_t)r * (DIM * DIM) + lane;
#pragma unroll
    for (int i = 0; i < 64; ++i) w[i] = wb[i * 64];
#pragma unroll
    for (int i = 0; i < 64; ++i) asm volatile("" : "+v"(w[i]));

    const int C = 32;
    for (int base = begin + wr * C; base < end; base += WPR * C) {
        const int lim = (base + C < end) ? base + C : end;
        int4 rv = rec[base];
        for (int k = base; k < lim; ++k) {
            const int kn = (k + 1 < lim) ? k + 1 : k;
            int4 rvn = rec[kn];                       // prefetch next record
            const int   si = __builtin_amdgcn_readfirstlane(rv.x);
            const int   di = __builtin_amdgcn_readfirstlane(rv.y);
            const float ak = __int_as_float(__builtin_amdgcn_readfirstlane(rv.z));
            const float* hp = h + (size_t)si * DIM;   // uniform -> s_load row
            float a0 = 0.f, a1 = 0.f, a2 = 0.f, a3 = 0.f;
#pragma unroll
            for (int i = 0; i < 64; i += 4) {
                a0 = fmaf(hp[i],     w[i],     a0);
                a1 = fmaf(hp[i + 1], w[i + 1], a1);
                a2 = fmaf(hp[i + 2], w[i + 2], a2);
                a3 = fmaf(hp[i + 3], w[i + 3], a3);
            }
            unsafeAtomicAdd(out + (size_t)di * DIM + lane,
                            ak * ((a0 + a1) + (a2 + a3)));
            rv = rvn;
        }
    }
}

// ---- phase 4: relu ----
__device__ void phase4(float4* __restrict__ out4) {
    const int t = threadIdx.x, bid = blockIdx.x;
    for (int i = bid * NTHR + t; i < N_NODES * 16; i += NBLK * NTHR) {
        float4 v = out4[i];
        v.x = fmaxf(v.x, 0.f); v.y = fmaxf(v.y, 0.f);
        v.z = fmaxf(v.z, 0.f); v.w = fmaxf(v.w, 0.f);
        out4[i] = v;
    }
}

__global__ __launch_bounds__(NTHR, 4) void mega(
    const float* h, const float4* he4,
    const int* src, const int* dst, const int* rel,
    const float* W_shared, const float* W_attn, const float* W_rel,
    float* out, int* counts, int* cursor,
    float* sn, float* dn, int4* rec) {
    cg::grid_group grid = cg::this_grid();
    phase0(counts, cursor);
    grid.sync();                                    // fence zeroing before flushes
    phase1(h, W_shared, W_attn, rel, sn, dn, (float4*)out, counts);
    grid.sync();
    phase2(he4, src, dst, rel, W_shared, W_attn, sn, dn, counts, cursor, rec);
    grid.sync();
    phase3(h, W_rel, counts, rec, out);
    grid.sync();
    phase4((float4*)out);
}

// fallback: phases as separate kernels (kernel boundaries give the fences)
__global__ void kz(int* counts, int* cursor) {
    if (threadIdx.x < NUM_RELS) { counts[threadIdx.x] = 0; cursor[threadIdx.x] = 0; }
}
__global__ __launch_bounds__(NTHR, 4) void kp1(const float* h, const float* Ws,
    const float* Wa, const int* rel, float* sn, float* dn, float* out,
    int* counts) {
    phase1(h, Ws, Wa, rel, sn, dn, (float4*)out, counts);
}
__global__ __launch_bounds__(NTHR, 4) void kp2(const float4* he4, const int* src,
    const int* dst, const int* rel, const float* Ws, const float* Wa,
    const float* sn, const float* dn, const int* counts, int* cursor, int4* rec) {
    phase2(he4, src, dst, rel, Ws, Wa, sn, dn, counts, cursor, rec);
}
__global__ __launch_bounds__(NTHR, 4) void kp3(const float* h, const float* W_rel,
    const int* counts, const int4* rec, float* out) {
    phase3(h, W_rel, counts, rec, out);
}
__global__ __launch_bounds__(NTHR, 4) void kp4(float* out) {
    phase4((float4*)out);
}

extern "C" void kernel_launch(void* const* d_in, const int* in_sizes, int n_in,
                              void* d_out, int out_size, void* d_ws, size_t ws_size,
                              hipStream_t stream) {
    const float*  h        = (const float*)d_in[0];
    const float4* he4      = (const float4*)d_in[1];
    const int*    src      = (const int*)d_in[2];
    const int*    dst      = (const int*)d_in[3];
    const int*    rel      = (const int*)d_in[4];
    const float*  W_shared = (const float*)d_in[5];
    const float*  W_attn   = (const float*)d_in[6];
    const float*  W_rel    = (const float*)d_in[7];
    float*        out      = (float*)d_out;

    int*   counts = (int*)d_ws + 192;
    int*   cursor = (int*)d_ws + 228;
    float* sn     = (float*)d_ws + 256;
    float* dn     = (float*)d_ws + 50256;
    int4*  rec    = (int4*)((int*)d_ws + 100352);

    void* args[] = { (void*)&h, (void*)&he4, (void*)&src, (void*)&dst, (void*)&rel,
                     (void*)&W_shared, (void*)&W_attn, (void*)&W_rel, (void*)&out,
                     (void*)&counts, (void*)&cursor, (void*)&sn, (void*)&dn, (void*)&rec };

    hipError_t err = hipLaunchCooperativeKernel((void*)mega, dim3(NBLK), dim3(NTHR),
                                                args, 0, stream);
    if (err != hipSuccess) {
        kz<<<1, 64, 0, stream>>>(counts, cursor);
        kp1<<<NBLK, NTHR, 0, stream>>>(h, W_shared, W_attn, rel, sn, dn, out, counts);
        kp2<<<NBLK, NTHR, 0, stream>>>(he4, src, dst, rel, W_shared, W_attn, sn, dn, counts, cursor, rec);
        kp3<<<NBLK, NTHR, 0, stream>>>(h, W_rel, counts, rec, out);
        kp4<<<NBLK, NTHR, 0, stream>>>(out);
    }
}

// Round 6
// 350.865 us; speedup vs baseline: 2.8778x; 2.8778x over previous
//
#include <hip/hip_runtime.h>
#include <math.h>

#define N_NODES 50000
#define N_EDGES 500000
#define NUM_RELS 16
#define G3 64          // k_mfma grid = 16*G3 = 1024 blocks (4/CU)

typedef _Float16 f16x8 __attribute__((ext_vector_type(8)));
typedef float    f32x4 __attribute__((ext_vector_type(4)));

// ---------------- ws layout (4-byte words) ----------------
// [192,208)     counts[16]
// [228,244)     cursor[16]
// [256,+N)      sn[N]
// [50256,+N)    dn[N]
// [100352,+E)   srcs[E]   (rel-sorted)
// [600352,+E)   dsts[E]
// [1100352,+E)  aes[E]
// total ~6.4 MB

// ---- zero the cross-block accumulators (own launch: fences before any flush) ----
__global__ void kz(int* counts, int* cursor) {
    if (threadIdx.x < NUM_RELS) { counts[threadIdx.x] = 0; cursor[threadIdx.x] = 0; }
}

// ---- node score scalars sn/dn, zero out, rel histogram -> counts ----
__global__ __launch_bounds__(256) void k_node(
    const float* __restrict__ h,
    const float* __restrict__ W_shared, const float* __restrict__ W_attn,
    const int* __restrict__ rel,
    float* __restrict__ sn, float* __restrict__ dn,
    float4* __restrict__ out4, int* __restrict__ counts) {
    __shared__ float sus[64], sud[64];
    __shared__ int hist[NUM_RELS];
    const int t = threadIdx.x, bid = blockIdx.x, nb = gridDim.x;
    if (t < 64) {
        float us = 0.f, ud = 0.f;
        for (int o = 0; o < 64; ++o) {
            float w = W_shared[o * 64 + t];
            us = fmaf(w, W_attn[o],       us);
            ud = fmaf(w, W_attn[128 + o], ud);
        }
        sus[t] = us; sud[t] = ud;
    }
    if (t < NUM_RELS) hist[t] = 0;
    __syncthreads();

    int n = bid * 256 + t;
    if (n < N_NODES) {
        const float* hp = h + (size_t)n * 64;
        float s = 0.f, d = 0.f;
#pragma unroll
        for (int i = 0; i < 64; i += 4) {
            float4 v = *(const float4*)(hp + i);
            s = fmaf(v.x, sus[i], s);     s = fmaf(v.y, sus[i + 1], s);
            s = fmaf(v.z, sus[i + 2], s); s = fmaf(v.w, sus[i + 3], s);
            d = fmaf(v.x, sud[i], d);     d = fmaf(v.y, sud[i + 1], d);
            d = fmaf(v.z, sud[i + 2], d); d = fmaf(v.w, sud[i + 3], d);
        }
        sn[n] = s; dn[n] = d;
        float4 z = make_float4(0.f, 0.f, 0.f, 0.f);
#pragma unroll
        for (int i = 0; i < 16; ++i) out4[(size_t)n * 16 + i] = z;
    }
    for (int e = bid * 256 + t; e < N_EDGES; e += nb * 256)
        atomicAdd(&hist[rel[e]], 1);
    __syncthreads();
    if (t < NUM_RELS && hist[t]) atomicAdd(&counts[t], hist[t]);
}

// ---- per-edge ae + scatter SoA records into rel-sorted order (verified R5 logic) ----
__global__ __launch_bounds__(256) void k_ae(
    const float4* __restrict__ he4,
    const int* __restrict__ src, const int* __restrict__ dst,
    const int* __restrict__ rel,
    const float* __restrict__ W_shared, const float* __restrict__ W_attn,
    const float* __restrict__ sn, const float* __restrict__ dn,
    const int* __restrict__ counts, int* __restrict__ cursor,
    int* __restrict__ srcs, int* __restrict__ dsts, float* __restrict__ aes) {
    __shared__ float sve[64];
    __shared__ int hist[NUM_RELS], bbase[NUM_RELS], soffs[NUM_RELS];
    const int t = threadIdx.x, bid = blockIdx.x, nb = gridDim.x;
    if (t < 64) {
        float ve = 0.f;
        for (int o = 0; o < 64; ++o)
            ve = fmaf(W_shared[o * 64 + t], W_attn[64 + o], ve);
        sve[t] = ve;
    }
    if (t == 0) {
        int acc = 0;
        for (int j = 0; j < NUM_RELS; ++j) { soffs[j] = acc; acc += counts[j]; }
    }
    for (int e0 = bid * 256; e0 < N_EDGES; e0 += nb * 256) {
        __syncthreads();
        if (t < NUM_RELS) hist[t] = 0;
        __syncthreads();
        int e = e0 + t;
        bool valid = (e < N_EDGES);
        int r = 0, lpos = 0, s_ = 0, d_ = 0; float aev = 0.f;
        if (valid) {
            s_ = src[e]; d_ = dst[e]; r = rel[e];
            const float4* hr = he4 + (size_t)e * 16;
            float acc = 0.f;
#pragma unroll
            for (int i = 0; i < 16; ++i) {
                float4 v = hr[i];
                float4 u = *(const float4*)(sve + 4 * i);
                acc += v.x * u.x + v.y * u.y + v.z * u.z + v.w * u.w;
            }
            aev = acc + sn[s_] + dn[d_];
            lpos = atomicAdd(&hist[r], 1);
        }
        __syncthreads();
        if (t < NUM_RELS) bbase[t] = hist[t] ? atomicAdd(&cursor[t], hist[t]) : 0;
        __syncthreads();
        if (valid) {
            int p = soffs[r] + bbase[r] + lpos;
            srcs[p] = s_; dsts[p] = d_; aes[p] = aev;
        }
    }
}

// ---- main: MFMA split-fp16. wave=relation, 16-edge batches.
// A[m=lane&15][k=quad*8+j] (h rows), B[k=quad*8+j][n=lane&15] (W_rel),
// D row=quad*4+reg, col=lane&15. 3-term hi/lo for fp32 accuracy. ----
__global__ __launch_bounds__(256, 4) void k_mfma(
    const float* __restrict__ h, const float* __restrict__ W_rel,
    const int* __restrict__ counts,
    const int* __restrict__ srcs, const int* __restrict__ dsts,
    const float* __restrict__ aes, float* __restrict__ out)
{
    const int t = threadIdx.x;
    const int lane = t & 63;
    const int quad = lane >> 4;
    const int col  = lane & 15;
    const int wib  = t >> 6;
    const int r    = blockIdx.x & 15;
    const int g    = blockIdx.x >> 4;
    const int wr   = g * 4 + wib;
    const int WPR  = G3 * 4;

    int begin = 0, cr = 0;
#pragma unroll
    for (int j = 0; j < NUM_RELS; ++j) {
        int c = counts[j];
        if (j < r) begin += c;
        if (j == r) cr = c;
    }
    begin = __builtin_amdgcn_readfirstlane(begin);
    const int end = __builtin_amdgcn_readfirstlane(begin + cr);

    const float* Wb = W_rel + (size_t)r * 4096;

    for (int half = 0; half < 2; ++half) {
        // B fragments for the two n-tiles of this half (loop-invariant)
        f16x8 bh[2][2], bl[2][2];
#pragma unroll
        for (int kb = 0; kb < 2; ++kb)
#pragma unroll
            for (int n2 = 0; n2 < 2; ++n2)
#pragma unroll
                for (int j = 0; j < 8; ++j) {
                    float w = Wb[(kb * 32 + quad * 8 + j) * 64 + (half * 2 + n2) * 16 + col];
                    _Float16 hi = (_Float16)w;
                    bh[kb][n2][j] = hi;
                    bl[kb][n2][j] = (_Float16)(w - (float)hi);
                }

        for (int base = begin + wr * 16; base < end; base += WPR * 16) {
            int m16 = end - base; if (m16 > 16) m16 = 16;
            const int ridx = base + (col < m16 ? col : m16 - 1);
            const int   sv = srcs[ridx];
            const int   dv = dsts[ridx];
            const float av = (col < m16) ? aes[ridx] : 0.f;   // padded rows add 0

            // A fragments (hi/lo split on the fly; h row L2-resident)
            f16x8 ah[2], al[2];
            const float* hp = h + (size_t)sv * 64 + quad * 8;
#pragma unroll
            for (int kb = 0; kb < 2; ++kb) {
                float4 x = *(const float4*)(hp + kb * 32);
                float4 y = *(const float4*)(hp + kb * 32 + 4);
                float xs[8] = {x.x, x.y, x.z, x.w, y.x, y.y, y.z, y.w};
#pragma unroll
                for (int j = 0; j < 8; ++j) {
                    _Float16 hi = (_Float16)xs[j];
                    ah[kb][j] = hi;
                    al[kb][j] = (_Float16)(xs[j] - (float)hi);
                }
            }

            f32x4 acc0 = {0.f, 0.f, 0.f, 0.f};
            f32x4 acc1 = {0.f, 0.f, 0.f, 0.f};
#pragma unroll
            for (int kb = 0; kb < 2; ++kb) {
                acc0 = __builtin_amdgcn_mfma_f32_16x16x32_f16(ah[kb], bh[kb][0], acc0, 0, 0, 0);
                acc0 = __builtin_amdgcn_mfma_f32_16x16x32_f16(ah[kb], bl[kb][0], acc0, 0, 0, 0);
                acc0 = __builtin_amdgcn_mfma_f32_16x16x32_f16(al[kb], bh[kb][0], acc0, 0, 0, 0);
                acc1 = __builtin_amdgcn_mfma_f32_16x16x32_f16(ah[kb], bh[kb][1], acc1, 0, 0, 0);
                acc1 = __builtin_amdgcn_mfma_f32_16x16x32_f16(ah[kb], bl[kb][1], acc1, 0, 0, 0);
                acc1 = __builtin_amdgcn_mfma_f32_16x16x32_f16(al[kb], bh[kb][1], acc1, 0, 0, 0);
            }

            // epilogue: row m = quad*4+reg lives in lane m (<16) for dv/av
#pragma unroll
            for (int reg = 0; reg < 4; ++reg) {
                const int m = quad * 4 + reg;
                const int   dm = __shfl(dv, m, 64);
                const float am = __shfl(av, m, 64);
                float* op = out + (size_t)dm * 64 + half * 32 + col;
                unsafeAtomicAdd(op,      am * acc0[reg]);
                unsafeAtomicAdd(op + 16, am * acc1[reg]);
            }
        }
    }
}

// ---- relu ----
__global__ __launch_bounds__(256) void k_relu(float4* __restrict__ out4) {
    for (int i = blockIdx.x * 256 + threadIdx.x; i < N_NODES * 16; i += gridDim.x * 256) {
        float4 v = out4[i];
        v.x = fmaxf(v.x, 0.f); v.y = fmaxf(v.y, 0.f);
        v.z = fmaxf(v.z, 0.f); v.w = fmaxf(v.w, 0.f);
        out4[i] = v;
    }
}

extern "C" void kernel_launch(void* const* d_in, const int* in_sizes, int n_in,
                              void* d_out, int out_size, void* d_ws, size_t ws_size,
                              hipStream_t stream) {
    const float*  h        = (const float*)d_in[0];
    const float4* he4      = (const float4*)d_in[1];
    const int*    src      = (const int*)d_in[2];
    const int*    dst      = (const int*)d_in[3];
    const int*    rel      = (const int*)d_in[4];
    const float*  W_shared = (const float*)d_in[5];
    const float*  W_attn   = (const float*)d_in[6];
    const float*  W_rel    = (const float*)d_in[7];
    float*        out      = (float*)d_out;

    int*   counts = (int*)d_ws + 192;
    int*   cursor = (int*)d_ws + 228;
    float* sn     = (float*)d_ws + 256;
    float* dn     = (float*)d_ws + 50256;
    int*   srcs   = (int*)d_ws + 100352;
    int*   dsts   = (int*)d_ws + 600352;
    float* aes    = (float*)d_ws + 1100352;

    kz<<<1, 64, 0, stream>>>(counts, cursor);
    k_node<<<(N_NODES + 255) / 256, 256, 0, stream>>>(h, W_shared, W_attn, rel,
                                                      sn, dn, (float4*)out, counts);
    k_ae<<<1024, 256, 0, stream>>>(he4, src, dst, rel, W_shared, W_attn,
                                   sn, dn, counts, cursor, srcs, dsts, aes);
    k_mfma<<<NUM_RELS * G3, 256, 0, stream>>>(h, W_rel, counts, srcs, dsts, aes, out);
    k_relu<<<1024, 256, 0, stream>>>((float4*)out);
}